// Round 1
// 303.589 us; speedup vs baseline: 1.0173x; 1.0173x over previous
//
#include <hip/hip_runtime.h>
#include <math.h>

#define NF 8
#define NQ 300
#define HSZ 96
#define WSZ 96
#define HW (HSZ*WSZ)        // 9216
#define DTOT (NF*HW)        // 73728
#define NBF 16              // bs*NF

// ws layout (float indices)
#define WS_TGTY  0           // [16][96]  max over h, indexed [bf][w]
#define WS_TGTX  1536        // [16][96]  max over w, indexed [bf][h]
#define WS_TSUM  3072        // [16]
#define WS_YSUM  3088        // [16]
#define WS_XSUM  3104        // [16]
#define WS_TBITS 3136        // [16][288] uint bitmask of tmask!=0 (LSB-first per 32 elems)
#define WS_PBITS 7744        // [2][288]  uint bitmask of vpad!=0
#define WS_PART  8320        // [2][300][8][8] partials, contiguous per (b,q)

__device__ __forceinline__ float sigmoid_fast(float x) {
    float e = __expf(-fabsf(x));
    float inv = __builtin_amdgcn_rcpf(1.f + e);
    return x >= 0.f ? inv : e * inv;
}

// ---------------------------------------------------------------------------
// targets_kernel: one block (1024 thr) per (b,f).
//  - projections tgtY (max over h), tgtX (max over w), sums
//  - bit-pack tmask; f==0 blocks also bit-pack vpad for their b
// ---------------------------------------------------------------------------
#define NTT 1024
__global__ __launch_bounds__(NTT)
void targets_kernel(const float* __restrict__ tm, const unsigned char* __restrict__ vpad,
                    float* __restrict__ ws) {
    int bf = blockIdx.x, t = threadIdx.x;
    int lane = t & 63, wid = t >> 6;
    __shared__ float tile[HSZ * 97];
    __shared__ float redt[16 * 3];
    const float* base = tm + (size_t)bf * HW;
    unsigned* tbw = (unsigned*)(ws + WS_TBITS) + bf * 288;

    float tsum = 0.f;
    #pragma unroll
    for (int it = 0; it < 9; ++it) {
        int e = it * NTT + t;
        float v = base[e];
        tsum += v;
        tile[e + e / 96] = v;                       // stride-97 padded
        unsigned long long m = __ballot(v != 0.f);
        int word = it * 32 + wid * 2;
        if (lane == 0)       tbw[word]     = (unsigned)m;
        else if (lane == 32) tbw[word + 1] = (unsigned)(m >> 32);
    }
    if ((bf & 7) == 0) {                            // pack vpad for this b
        const unsigned char* vb = vpad + (size_t)(bf >> 3) * HW;
        unsigned* pbw = (unsigned*)(ws + WS_PBITS) + (bf >> 3) * 288;
        #pragma unroll
        for (int it = 0; it < 9; ++it) {
            int e = it * NTT + t;
            unsigned long long m = __ballot(vb[e] != 0);
            int word = it * 32 + wid * 2;
            if (lane == 0)       pbw[word]     = (unsigned)m;
            else if (lane == 32) pbw[word + 1] = (unsigned)(m >> 32);
        }
    }
    __syncthreads();

    float ysum = 0.f, xsum = 0.f;
    if (t < 96) {
        float m = -INFINITY;
        #pragma unroll 8
        for (int h = 0; h < HSZ; ++h) m = fmaxf(m, tile[h * 97 + t]);
        ws[WS_TGTY + bf * 96 + t] = m;
        ysum = m;
    } else if (t < 192) {
        int hh = t - 96;
        float m = -INFINITY;
        #pragma unroll 8
        for (int w = 0; w < WSZ; ++w) m = fmaxf(m, tile[hh * 97 + w]);
        ws[WS_TGTX + bf * 96 + hh] = m;
        xsum = m;
    }
    float s0 = tsum, s1 = ysum, s2 = xsum;
    #pragma unroll
    for (int off = 32; off > 0; off >>= 1) {
        s0 += __shfl_down(s0, off, 64);
        s1 += __shfl_down(s1, off, 64);
        s2 += __shfl_down(s2, off, 64);
    }
    if (lane == 0) { redt[wid * 3] = s0; redt[wid * 3 + 1] = s1; redt[wid * 3 + 2] = s2; }
    __syncthreads();
    if (t == 0) {
        float a0 = 0.f, a1 = 0.f, a2 = 0.f;
        #pragma unroll
        for (int w = 0; w < 16; ++w) {
            a0 += redt[w * 3]; a1 += redt[w * 3 + 1]; a2 += redt[w * 3 + 2];
        }
        ws[WS_TSUM + bf] = a0;
        ws[WS_YSUM + bf] = a1;
        ws[WS_XSUM + bf] = a2;
    }
}

// ---------------------------------------------------------------------------
// partial_kernel: one block (192 thr = 8x24) per (b,f,q).
// Column-stationary mapping: thread owns 4 fixed columns (w4=t%24), rows 8k+t/24.
// Column maxes in registers; row maxes via [96][25] LDS; 2 barriers total.
// ---------------------------------------------------------------------------
#define NTP 192
__global__ __launch_bounds__(NTP, 4)
void partial_kernel(const float* __restrict__ masks, const float* __restrict__ ws,
                    float* __restrict__ part) {
    int bid = blockIdx.x;
    int bf = bid / NQ;
    int q  = bid - bf * NQ;
    int b  = bf >> 3, f = bf & 7;
    int t  = threadIdx.x;
    int w4 = t % 24;                 // fixed float4-column group
    int r0 = t / 24;                 // 0..7
    int wsh = (t & 7) * 4;           // nibble shift within bit-word (uniform per thread)

    __shared__ float rp[96 * 25];    // row-max partials [h][w4], +1 pad
    __shared__ float cp[8 * 100];    // col-max partials [r0][w], +4 pad
    __shared__ float red[3][8];

    const float4* mrow = (const float4*)(masks + (size_t)bid * HW);
    const unsigned* tbw = (const unsigned*)(ws + WS_TBITS) + bf * 288;
    const unsigned* pbw = (const unsigned*)(ws + WS_PBITS) + b * 288;

    float focal = 0.f, dnum = 0.f, dden = 0.f;
    float cm0 = -INFINITY, cm1 = -INFINITY, cm2 = -INFINITY, cm3 = -INFINITY;

    #pragma unroll
    for (int k = 0; k < 12; ++k) {
        int i4 = k * NTP + t;
        float4 xv = mrow[i4];
        unsigned tn = (tbw[k * 24 + (t >> 3)] >> wsh) & 0xFu;
        unsigned pn = (pbw[k * 24 + (t >> 3)] >> wsh) & 0xFu;
        float xs[4] = {xv.x, xv.y, xv.z, xv.w};
        if (pn) {                                     // vpad==0 in practice: skipped
            #pragma unroll
            for (int j = 0; j < 4; ++j) if ((pn >> j) & 1u) xs[j] = 0.f;
        }
        float rmx = -INFINITY;
        #pragma unroll
        for (int j = 0; j < 4; ++j) {
            float x = xs[j];
            float tg = (float)((tn >> j) & 1u);       // tmask is {0,1}
            float e = __expf(-fabsf(x));
            float se = 1.f + e;
            float inv = __builtin_amdgcn_rcpf(se);
            float s = x >= 0.f ? inv : e * inv;       // sigmoid(x)
            float L = __logf(se);                     // log1p(exp(-|x|))
            float ce = fmaf(-x, tg, fmaxf(x, 0.f) + L);
            float omp = fmaf(tg, fmaf(-2.f, s, 1.f), s);   // 1 - p_t
            float at = fmaf(tg, -0.5f, 0.75f);             // alpha_t
            focal = fmaf(at * ce, omp * omp, focal);
            dnum = fmaf(s, tg, dnum);
            dden += s;
            rmx = fmaxf(rmx, x);
        }
        cm0 = fmaxf(cm0, xs[0]); cm1 = fmaxf(cm1, xs[1]);
        cm2 = fmaxf(cm2, xs[2]); cm3 = fmaxf(cm3, xs[3]);
        rp[(8 * k + r0) * 25 + w4] = rmx;
    }
    {
        float4 cmv = {cm0, cm1, cm2, cm3};
        *(float4*)&cp[r0 * 100 + w4 * 4] = cmv;
    }
    __syncthreads();

    float v0 = focal, v1 = dnum, v2 = dden, v3 = 0.f, v4 = 0.f, v5 = 0.f, v6 = 0.f;
    if (t < 96) {                                     // y-projection (max over h)
        float m = cp[t];
        #pragma unroll
        for (int p = 1; p < 8; ++p) m = fmaxf(m, cp[p * 100 + t]);
        float sg = sigmoid_fast(m);
        v4 = sg;
        v3 = sg * ws[WS_TGTY + bf * 96 + t];
    } else {                                          // x-projection (max over w)
        int r = t - 96;
        float m = rp[r * 25];
        #pragma unroll
        for (int c = 1; c < 24; ++c) m = fmaxf(m, rp[r * 25 + c]);
        float sg = sigmoid_fast(m);
        v6 = sg;
        v5 = sg * ws[WS_TGTX + bf * 96 + r];
    }
    #pragma unroll
    for (int off = 32; off > 0; off >>= 1) {
        v0 += __shfl_down(v0, off, 64);
        v1 += __shfl_down(v1, off, 64);
        v2 += __shfl_down(v2, off, 64);
        v3 += __shfl_down(v3, off, 64);
        v4 += __shfl_down(v4, off, 64);
        v5 += __shfl_down(v5, off, 64);
        v6 += __shfl_down(v6, off, 64);
    }
    int wid = t >> 6, lane = t & 63;
    if (lane == 0) {
        red[wid][0] = v0; red[wid][1] = v1; red[wid][2] = v2; red[wid][3] = v3;
        red[wid][4] = v4; red[wid][5] = v5; red[wid][6] = v6;
    }
    __syncthreads();
    if (t == 0) {
        float* o = part + (size_t)((b * NQ + q) * NF + f) * 8;
        #pragma unroll
        for (int i = 0; i < 7; ++i) o[i] = red[0][i] + red[1][i] + red[2][i];
    }
}

// ---------------------------------------------------------------------------
// combine: one thread per (b,q); part is contiguous 64 floats per thread now
// ---------------------------------------------------------------------------
#define NTC 64
__global__ __launch_bounds__(NTC)
void combine_kernel(const float* __restrict__ logits, const float* __restrict__ boxes,
                    const float* __restrict__ tbox, const int* __restrict__ tvalid,
                    const float* __restrict__ ws, float* __restrict__ out) {
    int gid = blockIdx.x * NTC + threadIdx.x;
    if (gid >= 2 * NQ) return;
    int b = gid / NQ, q = gid - b * NQ;

    const float* pbase = ws + WS_PART + (size_t)gid * (NF * 8);
    float focal = 0.f, dnum = 0.f, dden = 0.f;
    float pYn = 0.f, pYd = 0.f, pXn = 0.f, pXd = 0.f;
    float tsum = 0.f, ysum = 0.f, xsum = 0.f;
    #pragma unroll
    for (int f = 0; f < NF; ++f) {
        int bf = b * NF + f;
        const float* p = pbase + f * 8;
        focal += p[0]; dnum += p[1]; dden += p[2];
        pYn += p[3]; pYd += p[4]; pXn += p[5]; pXd += p[6];
        tsum += ws[WS_TSUM + bf];
        ysum += ws[WS_YSUM + bf];
        xsum += ws[WS_XSUM + bf];
    }
    float cost_mask = focal / (float)DTOT;
    float cost_dice = -(2.f * dnum + 1.f) / (dden + tsum + 1.f);
    float coefY = (2.f * pYn + 1.f) / (pYd + ysum + 1.f);
    float coefX = (2.f * pXn + 1.f) / (pXd + xsum + 1.f);
    float cost_proj = -0.5f * (coefY + coefX);

    float wsum = 0.f, cls = 0.f, cb = 0.f, cg = 0.f;
    #pragma unroll
    for (int f = 0; f < NF; ++f) {
        float wv = (tvalid[b * NF + f] != 0) ? 1.f : 0.f;
        wsum += wv;
        float lg = logits[(b * NF + f) * NQ + q];
        float p = sigmoid_fast(lg);
        float negc = 0.75f * p * p * (-__logf(1.f - p + 1e-8f));
        float posc = 0.25f * (1.f - p) * (1.f - p) * (-__logf(p + 1e-8f));
        cls += (posc - negc) * wv;

        const float* bx = boxes + (size_t)((b * NF + f) * NQ + q) * 4;
        const float* tb = tbox + (b * NF + f) * 4;
        float cx = bx[0], cy = bx[1], bw = bx[2], bh = bx[3];
        float tcx = tb[0], tcy = tb[1], tbw = tb[2], tbh = tb[3];
        cb += fabsf(cx - tcx) + fabsf(cy - tcy) + fabsf(bw - tbw) + fabsf(bh - tbh);
        float sx1 = cx - 0.5f * bw, sy1 = cy - 0.5f * bh;
        float sx2 = cx + 0.5f * bw, sy2 = cy + 0.5f * bh;
        float tx1 = tcx - 0.5f * tbw, ty1 = tcy - 0.5f * tbh;
        float tx2 = tcx + 0.5f * tbw, ty2 = tcy + 0.5f * tbh;
        float a1 = (sx2 - sx1) * (sy2 - sy1), a2 = (tx2 - tx1) * (ty2 - ty1);
        float iw = fmaxf(fminf(sx2, tx2) - fmaxf(sx1, tx1), 0.f);
        float ih = fmaxf(fminf(sy2, ty2) - fmaxf(sy1, ty1), 0.f);
        float inter = iw * ih;
        float uni = a1 + a2 - inter;
        float iou = inter / uni;
        float cw = fmaxf(fmaxf(sx2, tx2) - fminf(sx1, tx1), 0.f);
        float chh = fmaxf(fmaxf(sy2, ty2) - fminf(sy1, ty1), 0.f);
        float areac = cw * chh;
        cg += -(iou - (areac - uni) / areac);
    }
    cls /= wsum;
    cb *= 0.125f;
    cg *= 0.125f;
    out[b * NQ + q] = cls + cb + cg + cost_mask + cost_dice + cost_proj;
}

#define NT 256
__global__ __launch_bounds__(NT)
void argmin_kernel(float* __restrict__ out, int write_idx) {
    int b = blockIdx.x, t = threadIdx.x;
    float best = INFINITY;
    int bi = 0x7fffffff;
    for (int q = t; q < NQ; q += NT) {
        float v = out[b * NQ + q];
        if (v < best) { best = v; bi = q; }
    }
    #pragma unroll
    for (int off = 32; off > 0; off >>= 1) {
        float ov = __shfl_down(best, off, 64);
        int oi = __shfl_down(bi, off, 64);
        if (ov < best || (ov == best && oi < bi)) { best = ov; bi = oi; }
    }
    __shared__ float rv[4];
    __shared__ int ri[4];
    int wid = t >> 6, lane = t & 63;
    if (lane == 0) { rv[wid] = best; ri[wid] = bi; }
    __syncthreads();
    if (t == 0 && write_idx) {
        #pragma unroll
        for (int w = 1; w < 4; ++w) {
            if (rv[w] < best || (rv[w] == best && ri[w] < bi)) { best = rv[w]; bi = ri[w]; }
        }
        out[2 * NQ + b] = (float)bi;       // src_ind
        out[2 * NQ + 2 + b] = 0.f;         // tgt_ind
    }
}

extern "C" void kernel_launch(void* const* d_in, const int* in_sizes, int n_in,
                              void* d_out, int out_size, void* d_ws, size_t ws_size,
                              hipStream_t stream) {
    const float* logits = (const float*)d_in[0];
    const float* boxes  = (const float*)d_in[1];
    const float* masks  = (const float*)d_in[2];
    const float* tmask  = (const float*)d_in[3];
    const float* tbox   = (const float*)d_in[4];
    const int*   tvalid = (const int*)d_in[5];
    const unsigned char* vpad = (const unsigned char*)d_in[6];
    float* out = (float*)d_out;
    float* ws  = (float*)d_ws;

    targets_kernel<<<NBF, NTT, 0, stream>>>(tmask, vpad, ws);
    partial_kernel<<<NBF * NQ, NTP, 0, stream>>>(masks, ws, ws + WS_PART);
    combine_kernel<<<(2 * NQ + NTC - 1) / NTC, NTC, 0, stream>>>(logits, boxes, tbox,
                                                                 tvalid, ws, out);
    int write_idx = (out_size >= 2 * NQ + 4) ? 1 : 0;
    argmin_kernel<<<2, NT, 0, stream>>>(out, write_idx);
}

// Round 2
// 293.100 us; speedup vs baseline: 1.0537x; 1.0358x over previous
//
#include <hip/hip_runtime.h>
#include <math.h>

#define NF 8
#define NQ 300
#define HSZ 96
#define WSZ 96
#define HW (HSZ*WSZ)        // 9216
#define DTOT (NF*HW)        // 73728
#define NBF 16              // bs*NF

// ws layout (float indices)
#define WS_TGTY  0           // [16][96]  max over h, indexed [bf][w]
#define WS_TGTX  1536        // [16][96]  max over w, indexed [bf][h]
#define WS_TSUM  3072        // [16]
#define WS_YSUM  3088        // [16]
#define WS_XSUM  3104        // [16]
#define WS_TBITS 3136        // [16][288] uint bitmask of tmask!=0 (LSB-first per 32 elems)
#define WS_PBITS 7744        // [2][288]  uint bitmask of vpad!=0
#define WS_PART  8320        // [2][300][8][8] partials, contiguous per (b,q)

__device__ __forceinline__ float sigmoid_fast(float x) {
    float e = __expf(-fabsf(x));
    float inv = __builtin_amdgcn_rcpf(1.f + e);
    return x >= 0.f ? inv : e * inv;
}

// ---------------------------------------------------------------------------
// targets_kernel: one block (1024 thr) per (b,f).
//  - projections tgtY (max over h), tgtX (max over w), sums
//  - bit-pack tmask; f==0 blocks also bit-pack vpad for their b
// ---------------------------------------------------------------------------
#define NTT 1024
__global__ __launch_bounds__(NTT)
void targets_kernel(const float* __restrict__ tm, const unsigned char* __restrict__ vpad,
                    float* __restrict__ ws) {
    int bf = blockIdx.x, t = threadIdx.x;
    int lane = t & 63, wid = t >> 6;
    __shared__ float tile[HSZ * 97];
    __shared__ float redt[16 * 3];
    const float* base = tm + (size_t)bf * HW;
    unsigned* tbw = (unsigned*)(ws + WS_TBITS) + bf * 288;

    float tsum = 0.f;
    #pragma unroll
    for (int it = 0; it < 9; ++it) {
        int e = it * NTT + t;
        float v = base[e];
        tsum += v;
        tile[e + e / 96] = v;                       // stride-97 padded
        unsigned long long m = __ballot(v != 0.f);
        int word = it * 32 + wid * 2;
        if (lane == 0)       tbw[word]     = (unsigned)m;
        else if (lane == 32) tbw[word + 1] = (unsigned)(m >> 32);
    }
    if ((bf & 7) == 0) {                            // pack vpad for this b
        const unsigned char* vb = vpad + (size_t)(bf >> 3) * HW;
        unsigned* pbw = (unsigned*)(ws + WS_PBITS) + (bf >> 3) * 288;
        #pragma unroll
        for (int it = 0; it < 9; ++it) {
            int e = it * NTT + t;
            unsigned long long m = __ballot(vb[e] != 0);
            int word = it * 32 + wid * 2;
            if (lane == 0)       pbw[word]     = (unsigned)m;
            else if (lane == 32) pbw[word + 1] = (unsigned)(m >> 32);
        }
    }
    __syncthreads();

    float ysum = 0.f, xsum = 0.f;
    if (t < 96) {
        float m = -INFINITY;
        #pragma unroll 8
        for (int h = 0; h < HSZ; ++h) m = fmaxf(m, tile[h * 97 + t]);
        ws[WS_TGTY + bf * 96 + t] = m;
        ysum = m;
    } else if (t < 192) {
        int hh = t - 96;
        float m = -INFINITY;
        #pragma unroll 8
        for (int w = 0; w < WSZ; ++w) m = fmaxf(m, tile[hh * 97 + w]);
        ws[WS_TGTX + bf * 96 + hh] = m;
        xsum = m;
    }
    float s0 = tsum, s1 = ysum, s2 = xsum;
    #pragma unroll
    for (int off = 32; off > 0; off >>= 1) {
        s0 += __shfl_down(s0, off, 64);
        s1 += __shfl_down(s1, off, 64);
        s2 += __shfl_down(s2, off, 64);
    }
    if (lane == 0) { redt[wid * 3] = s0; redt[wid * 3 + 1] = s1; redt[wid * 3 + 2] = s2; }
    __syncthreads();
    if (t == 0) {
        float a0 = 0.f, a1 = 0.f, a2 = 0.f;
        #pragma unroll
        for (int w = 0; w < 16; ++w) {
            a0 += redt[w * 3]; a1 += redt[w * 3 + 1]; a2 += redt[w * 3 + 2];
        }
        ws[WS_TSUM + bf] = a0;
        ws[WS_YSUM + bf] = a1;
        ws[WS_XSUM + bf] = a2;
    }
}

// ---------------------------------------------------------------------------
// partial_kernel: one block (384 thr = 16x24, 6 waves) per (b,f,q).
// Column-stationary: thread owns 4 fixed columns (w4=t%24), rows 16k+t/24.
// ALL global loads batch-issued into registers before compute (6 float4 +
// 6 bitwords in flight per thread) -> deep memory pipeline at 30 waves/CU.
// ---------------------------------------------------------------------------
#define NTP 384
__global__ __launch_bounds__(NTP, 8)
void partial_kernel(const float* __restrict__ masks, const float* __restrict__ ws,
                    float* __restrict__ part) {
    int bid = blockIdx.x;
    int bf = bid / NQ;
    int q  = bid - bf * NQ;
    int b  = bf >> 3, f = bf & 7;
    int t  = threadIdx.x;
    int w4 = t % 24;                 // fixed float4-column group
    int r0 = t / 24;                 // 0..15
    int wsh = (t & 7) * 4;           // nibble shift within bit-word (uniform across k)

    __shared__ float rp[96 * 25];    // row-max partials [h][w4], +1 pad
    __shared__ float cp[16 * 100];   // col-max partials [r0][w], +4 pad
    __shared__ float red[6][8];

    const float4* mrow = (const float4*)(masks + (size_t)bid * HW);
    const unsigned* tbw = (const unsigned*)(ws + WS_TBITS) + bf * 288;
    const unsigned* pbw = (const unsigned*)(ws + WS_PBITS) + b * 288;

    // ---- batch-issue all global loads (payload stays in registers) ----
    float4 xv[6];
    unsigned tw[6];
    #pragma unroll
    for (int k = 0; k < 6; ++k) xv[k] = mrow[k * NTP + t];
    #pragma unroll
    for (int k = 0; k < 6; ++k) tw[k] = tbw[k * 48 + (t >> 3)];

    float focal = 0.f, dnum = 0.f, dden = 0.f;
    float cm0 = -INFINITY, cm1 = -INFINITY, cm2 = -INFINITY, cm3 = -INFINITY;

    #pragma unroll
    for (int k = 0; k < 6; ++k) {
        unsigned tn = (tw[k] >> wsh) & 0xFu;
        unsigned pn = (pbw[k * 48 + (t >> 3)] >> wsh) & 0xFu;
        float xs[4] = {xv[k].x, xv[k].y, xv[k].z, xv[k].w};
        if (pn) {                                     // vpad==0 in practice: skipped
            #pragma unroll
            for (int j = 0; j < 4; ++j) if ((pn >> j) & 1u) xs[j] = 0.f;
        }
        float rmx = -INFINITY;
        #pragma unroll
        for (int j = 0; j < 4; ++j) {
            float x = xs[j];
            float tg = (float)((tn >> j) & 1u);       // tmask is {0,1}
            float e = __expf(-fabsf(x));
            float se = 1.f + e;
            float inv = __builtin_amdgcn_rcpf(se);
            float s = x >= 0.f ? inv : e * inv;       // sigmoid(x)
            float L = __logf(se);                     // log1p(exp(-|x|))
            float ce = fmaf(-x, tg, fmaxf(x, 0.f) + L);
            float omp = fmaf(tg, fmaf(-2.f, s, 1.f), s);   // 1 - p_t
            float at = fmaf(tg, -0.5f, 0.75f);             // alpha_t
            focal = fmaf(at * ce, omp * omp, focal);
            dnum = fmaf(s, tg, dnum);
            dden += s;
            rmx = fmaxf(rmx, x);
        }
        cm0 = fmaxf(cm0, xs[0]); cm1 = fmaxf(cm1, xs[1]);
        cm2 = fmaxf(cm2, xs[2]); cm3 = fmaxf(cm3, xs[3]);
        rp[(16 * k + r0) * 25 + w4] = rmx;
    }
    {
        float4 cmv = {cm0, cm1, cm2, cm3};
        *(float4*)&cp[r0 * 100 + w4 * 4] = cmv;
    }
    __syncthreads();

    float v0 = focal, v1 = dnum, v2 = dden, v3 = 0.f, v4 = 0.f, v5 = 0.f, v6 = 0.f;
    if (t < 96) {                                     // y-projection (max over h)
        float m = -INFINITY;
        #pragma unroll
        for (int p = 0; p < 16; ++p) m = fmaxf(m, cp[p * 100 + t]);
        float sg = sigmoid_fast(m);
        v4 = sg;
        v3 = sg * ws[WS_TGTY + bf * 96 + t];
    } else if (t < 192) {                             // x-projection (max over w)
        int r = t - 96;
        float m = rp[r * 25];
        #pragma unroll
        for (int c = 1; c < 24; ++c) m = fmaxf(m, rp[r * 25 + c]);
        float sg = sigmoid_fast(m);
        v6 = sg;
        v5 = sg * ws[WS_TGTX + bf * 96 + r];
    }
    #pragma unroll
    for (int off = 32; off > 0; off >>= 1) {
        v0 += __shfl_down(v0, off, 64);
        v1 += __shfl_down(v1, off, 64);
        v2 += __shfl_down(v2, off, 64);
        v3 += __shfl_down(v3, off, 64);
        v4 += __shfl_down(v4, off, 64);
        v5 += __shfl_down(v5, off, 64);
        v6 += __shfl_down(v6, off, 64);
    }
    int wid = t >> 6, lane = t & 63;
    if (lane == 0) {
        red[wid][0] = v0; red[wid][1] = v1; red[wid][2] = v2; red[wid][3] = v3;
        red[wid][4] = v4; red[wid][5] = v5; red[wid][6] = v6;
    }
    __syncthreads();
    if (t == 0) {
        float* o = part + (size_t)((b * NQ + q) * NF + f) * 8;
        #pragma unroll
        for (int i = 0; i < 7; ++i)
            o[i] = red[0][i] + red[1][i] + red[2][i] + red[3][i] + red[4][i] + red[5][i];
    }
}

// ---------------------------------------------------------------------------
// combine: one thread per (b,q); part is contiguous 64 floats per thread
// ---------------------------------------------------------------------------
#define NTC 64
__global__ __launch_bounds__(NTC)
void combine_kernel(const float* __restrict__ logits, const float* __restrict__ boxes,
                    const float* __restrict__ tbox, const int* __restrict__ tvalid,
                    const float* __restrict__ ws, float* __restrict__ out) {
    int gid = blockIdx.x * NTC + threadIdx.x;
    if (gid >= 2 * NQ) return;
    int b = gid / NQ, q = gid - b * NQ;

    const float* pbase = ws + WS_PART + (size_t)gid * (NF * 8);
    float focal = 0.f, dnum = 0.f, dden = 0.f;
    float pYn = 0.f, pYd = 0.f, pXn = 0.f, pXd = 0.f;
    float tsum = 0.f, ysum = 0.f, xsum = 0.f;
    #pragma unroll
    for (int f = 0; f < NF; ++f) {
        int bf = b * NF + f;
        const float* p = pbase + f * 8;
        focal += p[0]; dnum += p[1]; dden += p[2];
        pYn += p[3]; pYd += p[4]; pXn += p[5]; pXd += p[6];
        tsum += ws[WS_TSUM + bf];
        ysum += ws[WS_YSUM + bf];
        xsum += ws[WS_XSUM + bf];
    }
    float cost_mask = focal / (float)DTOT;
    float cost_dice = -(2.f * dnum + 1.f) / (dden + tsum + 1.f);
    float coefY = (2.f * pYn + 1.f) / (pYd + ysum + 1.f);
    float coefX = (2.f * pXn + 1.f) / (pXd + xsum + 1.f);
    float cost_proj = -0.5f * (coefY + coefX);

    float wsum = 0.f, cls = 0.f, cb = 0.f, cg = 0.f;
    #pragma unroll
    for (int f = 0; f < NF; ++f) {
        float wv = (tvalid[b * NF + f] != 0) ? 1.f : 0.f;
        wsum += wv;
        float lg = logits[(b * NF + f) * NQ + q];
        float p = sigmoid_fast(lg);
        float negc = 0.75f * p * p * (-__logf(1.f - p + 1e-8f));
        float posc = 0.25f * (1.f - p) * (1.f - p) * (-__logf(p + 1e-8f));
        cls += (posc - negc) * wv;

        const float* bx = boxes + (size_t)((b * NF + f) * NQ + q) * 4;
        const float* tb = tbox + (b * NF + f) * 4;
        float cx = bx[0], cy = bx[1], bw = bx[2], bh = bx[3];
        float tcx = tb[0], tcy = tb[1], tbw = tb[2], tbh = tb[3];
        cb += fabsf(cx - tcx) + fabsf(cy - tcy) + fabsf(bw - tbw) + fabsf(bh - tbh);
        float sx1 = cx - 0.5f * bw, sy1 = cy - 0.5f * bh;
        float sx2 = cx + 0.5f * bw, sy2 = cy + 0.5f * bh;
        float tx1 = tcx - 0.5f * tbw, ty1 = tcy - 0.5f * tbh;
        float tx2 = tcx + 0.5f * tbw, ty2 = tcy + 0.5f * tbh;
        float a1 = (sx2 - sx1) * (sy2 - sy1), a2 = (tx2 - tx1) * (ty2 - ty1);
        float iw = fmaxf(fminf(sx2, tx2) - fmaxf(sx1, tx1), 0.f);
        float ih = fmaxf(fminf(sy2, ty2) - fmaxf(sy1, ty1), 0.f);
        float inter = iw * ih;
        float uni = a1 + a2 - inter;
        float iou = inter / uni;
        float cw = fmaxf(fmaxf(sx2, tx2) - fminf(sx1, tx1), 0.f);
        float chh = fmaxf(fmaxf(sy2, ty2) - fminf(sy1, ty1), 0.f);
        float areac = cw * chh;
        cg += -(iou - (areac - uni) / areac);
    }
    cls /= wsum;
    cb *= 0.125f;
    cg *= 0.125f;
    out[b * NQ + q] = cls + cb + cg + cost_mask + cost_dice + cost_proj;
}

#define NT 256
__global__ __launch_bounds__(NT)
void argmin_kernel(float* __restrict__ out, int write_idx) {
    int b = blockIdx.x, t = threadIdx.x;
    float best = INFINITY;
    int bi = 0x7fffffff;
    for (int q = t; q < NQ; q += NT) {
        float v = out[b * NQ + q];
        if (v < best) { best = v; bi = q; }
    }
    #pragma unroll
    for (int off = 32; off > 0; off >>= 1) {
        float ov = __shfl_down(best, off, 64);
        int oi = __shfl_down(bi, off, 64);
        if (ov < best || (ov == best && oi < bi)) { best = ov; bi = oi; }
    }
    __shared__ float rv[4];
    __shared__ int ri[4];
    int wid = t >> 6, lane = t & 63;
    if (lane == 0) { rv[wid] = best; ri[wid] = bi; }
    __syncthreads();
    if (t == 0 && write_idx) {
        #pragma unroll
        for (int w = 1; w < 4; ++w) {
            if (rv[w] < best || (rv[w] == best && ri[w] < bi)) { best = rv[w]; bi = ri[w]; }
        }
        out[2 * NQ + b] = (float)bi;       // src_ind
        out[2 * NQ + 2 + b] = 0.f;         // tgt_ind
    }
}

extern "C" void kernel_launch(void* const* d_in, const int* in_sizes, int n_in,
                              void* d_out, int out_size, void* d_ws, size_t ws_size,
                              hipStream_t stream) {
    const float* logits = (const float*)d_in[0];
    const float* boxes  = (const float*)d_in[1];
    const float* masks  = (const float*)d_in[2];
    const float* tmask  = (const float*)d_in[3];
    const float* tbox   = (const float*)d_in[4];
    const int*   tvalid = (const int*)d_in[5];
    const unsigned char* vpad = (const unsigned char*)d_in[6];
    float* out = (float*)d_out;
    float* ws  = (float*)d_ws;

    targets_kernel<<<NBF, NTT, 0, stream>>>(tmask, vpad, ws);
    partial_kernel<<<NBF * NQ, NTP, 0, stream>>>(masks, ws, ws + WS_PART);
    combine_kernel<<<(2 * NQ + NTC - 1) / NTC, NTC, 0, stream>>>(logits, boxes, tbox,
                                                                 tvalid, ws, out);
    int write_idx = (out_size >= 2 * NQ + 4) ? 1 : 0;
    argmin_kernel<<<2, NT, 0, stream>>>(out, write_idx);
}

// Round 3
// 284.135 us; speedup vs baseline: 1.0869x; 1.0316x over previous
//
#include <hip/hip_runtime.h>
#include <math.h>

#define NF 8
#define NQ 300
#define HSZ 96
#define WSZ 96
#define HW (HSZ*WSZ)        // 9216
#define DTOT (NF*HW)        // 73728
#define NBF 16              // bs*NF

// ws layout (float indices)
#define WS_TGTY  0           // [16][96]  max over h, indexed [bf][w]
#define WS_TGTX  1536        // [16][96]  max over w, indexed [bf][h]
#define WS_TSUM  3072        // [16]
#define WS_YSUM  3088        // [16]
#define WS_XSUM  3104        // [16]
#define WS_TBITS 3136        // [16][288] uint bitmask of tmask!=0 (LSB-first per 32 elems)
#define WS_PBITS 7744        // [2][288]  uint bitmask of vpad!=0
#define WS_PART  8320        // [2][300][8][8] partials, contiguous per (b,q)

__device__ __forceinline__ float sigmoid_fast(float x) {
    float e = __expf(-fabsf(x));
    float inv = __builtin_amdgcn_rcpf(1.f + e);
    return x >= 0.f ? inv : e * inv;
}

// ---------------------------------------------------------------------------
// targets_kernel: one block (1024 thr) per (b,f).
//  - projections tgtY (max over h), tgtX (max over w), sums
//  - bit-pack tmask; f==0 blocks also bit-pack vpad for their b
// ---------------------------------------------------------------------------
#define NTT 1024
__global__ __launch_bounds__(NTT)
void targets_kernel(const float* __restrict__ tm, const unsigned char* __restrict__ vpad,
                    float* __restrict__ ws) {
    int bf = blockIdx.x, t = threadIdx.x;
    int lane = t & 63, wid = t >> 6;
    __shared__ float tile[HSZ * 97];
    __shared__ float redt[16 * 3];
    const float* base = tm + (size_t)bf * HW;
    unsigned* tbw = (unsigned*)(ws + WS_TBITS) + bf * 288;

    float tsum = 0.f;
    #pragma unroll
    for (int it = 0; it < 9; ++it) {
        int e = it * NTT + t;
        float v = base[e];
        tsum += v;
        tile[e + e / 96] = v;                       // stride-97 padded
        unsigned long long m = __ballot(v != 0.f);
        int word = it * 32 + wid * 2;
        if (lane == 0)       tbw[word]     = (unsigned)m;
        else if (lane == 32) tbw[word + 1] = (unsigned)(m >> 32);
    }
    if ((bf & 7) == 0) {                            // pack vpad for this b
        const unsigned char* vb = vpad + (size_t)(bf >> 3) * HW;
        unsigned* pbw = (unsigned*)(ws + WS_PBITS) + (bf >> 3) * 288;
        #pragma unroll
        for (int it = 0; it < 9; ++it) {
            int e = it * NTT + t;
            unsigned long long m = __ballot(vb[e] != 0);
            int word = it * 32 + wid * 2;
            if (lane == 0)       pbw[word]     = (unsigned)m;
            else if (lane == 32) pbw[word + 1] = (unsigned)(m >> 32);
        }
    }
    __syncthreads();

    float ysum = 0.f, xsum = 0.f;
    if (t < 96) {
        float m = -INFINITY;
        #pragma unroll 8
        for (int h = 0; h < HSZ; ++h) m = fmaxf(m, tile[h * 97 + t]);
        ws[WS_TGTY + bf * 96 + t] = m;
        ysum = m;
    } else if (t < 192) {
        int hh = t - 96;
        float m = -INFINITY;
        #pragma unroll 8
        for (int w = 0; w < WSZ; ++w) m = fmaxf(m, tile[hh * 97 + w]);
        ws[WS_TGTX + bf * 96 + hh] = m;
        xsum = m;
    }
    float s0 = tsum, s1 = ysum, s2 = xsum;
    #pragma unroll
    for (int off = 32; off > 0; off >>= 1) {
        s0 += __shfl_down(s0, off, 64);
        s1 += __shfl_down(s1, off, 64);
        s2 += __shfl_down(s2, off, 64);
    }
    if (lane == 0) { redt[wid * 3] = s0; redt[wid * 3 + 1] = s1; redt[wid * 3 + 2] = s2; }
    __syncthreads();
    if (t == 0) {
        float a0 = 0.f, a1 = 0.f, a2 = 0.f;
        #pragma unroll
        for (int w = 0; w < 16; ++w) {
            a0 += redt[w * 3]; a1 += redt[w * 3 + 1]; a2 += redt[w * 3 + 2];
        }
        ws[WS_TSUM + bf] = a0;
        ws[WS_YSUM + bf] = a1;
        ws[WS_XSUM + bf] = a2;
    }
}

// ---------------------------------------------------------------------------
// partial_kernel: one block (384 thr = 16x24, 6 waves) per (b,f,q).
// Column-stationary: thread owns 4 fixed columns (w4=t%24), rows 16k+t/24.
// ALL global loads (6 float4 + 6 tbits + 6 pbits) batch-issued into registers
// before compute. __launch_bounds__(384,6): VGPR cap ~85 so the compiler can
// hold the whole payload + schedule with ILP (cap-64 in prev round cramped it);
// occupancy 4 blocks/CU = 24 waves/CU.
// ---------------------------------------------------------------------------
#define NTP 384
__global__ __launch_bounds__(NTP, 6)
void partial_kernel(const float* __restrict__ masks, const float* __restrict__ ws,
                    float* __restrict__ part) {
    int bid = blockIdx.x;
    int bf = bid / NQ;
    int q  = bid - bf * NQ;
    int b  = bf >> 3, f = bf & 7;
    int t  = threadIdx.x;
    int w4 = t % 24;                 // fixed float4-column group
    int r0 = t / 24;                 // 0..15
    int wsh = (t & 7) * 4;           // nibble shift within bit-word (uniform across k)

    __shared__ float rp[96 * 25];    // row-max partials [h][w4], +1 pad
    __shared__ float cp[16 * 100];   // col-max partials [r0][w], +4 pad
    __shared__ float red[6][8];

    const float4* mrow = (const float4*)(masks + (size_t)bid * HW);
    const unsigned* tbw = (const unsigned*)(ws + WS_TBITS) + bf * 288;
    const unsigned* pbw = (const unsigned*)(ws + WS_PBITS) + b * 288;

    // ---- batch-issue all global loads (payload stays in registers) ----
    float4 xv[6];
    unsigned tw[6], pw[6];
    #pragma unroll
    for (int k = 0; k < 6; ++k) xv[k] = mrow[k * NTP + t];
    #pragma unroll
    for (int k = 0; k < 6; ++k) tw[k] = tbw[k * 48 + (t >> 3)];
    #pragma unroll
    for (int k = 0; k < 6; ++k) pw[k] = pbw[k * 48 + (t >> 3)];

    float focal = 0.f, dnum = 0.f, dden = 0.f;
    float cm0 = -INFINITY, cm1 = -INFINITY, cm2 = -INFINITY, cm3 = -INFINITY;

    #pragma unroll
    for (int k = 0; k < 6; ++k) {
        unsigned tn = (tw[k] >> wsh) & 0xFu;
        unsigned pn = (pw[k] >> wsh) & 0xFu;
        float xs[4] = {xv[k].x, xv[k].y, xv[k].z, xv[k].w};
        if (pn) {                                     // vpad==0 in practice: skipped
            #pragma unroll
            for (int j = 0; j < 4; ++j) if ((pn >> j) & 1u) xs[j] = 0.f;
        }
        float rmx = -INFINITY;
        #pragma unroll
        for (int j = 0; j < 4; ++j) {
            float x = xs[j];
            float tg = (float)((tn >> j) & 1u);       // tmask is {0,1}
            float e = __expf(-fabsf(x));
            float se = 1.f + e;
            float inv = __builtin_amdgcn_rcpf(se);
            float s = x >= 0.f ? inv : e * inv;       // sigmoid(x)
            float L = __logf(se);                     // log1p(exp(-|x|))
            float ce = fmaf(-x, tg, fmaxf(x, 0.f) + L);
            float omp = fmaf(tg, fmaf(-2.f, s, 1.f), s);   // 1 - p_t
            float at = fmaf(tg, -0.5f, 0.75f);             // alpha_t
            focal = fmaf(at * ce, omp * omp, focal);
            dnum = fmaf(s, tg, dnum);
            dden += s;
            rmx = fmaxf(rmx, x);
        }
        cm0 = fmaxf(cm0, xs[0]); cm1 = fmaxf(cm1, xs[1]);
        cm2 = fmaxf(cm2, xs[2]); cm3 = fmaxf(cm3, xs[3]);
        rp[(16 * k + r0) * 25 + w4] = rmx;
    }
    {
        float4 cmv = {cm0, cm1, cm2, cm3};
        *(float4*)&cp[r0 * 100 + w4 * 4] = cmv;
    }
    __syncthreads();

    float v0 = focal, v1 = dnum, v2 = dden, v3 = 0.f, v4 = 0.f, v5 = 0.f, v6 = 0.f;
    if (t < 96) {                                     // y-projection (max over h)
        float m = -INFINITY;
        #pragma unroll
        for (int p = 0; p < 16; ++p) m = fmaxf(m, cp[p * 100 + t]);
        float sg = sigmoid_fast(m);
        v4 = sg;
        v3 = sg * ws[WS_TGTY + bf * 96 + t];
    } else if (t < 192) {                             // x-projection (max over w)
        int r = t - 96;
        float m = rp[r * 25];
        #pragma unroll
        for (int c = 1; c < 24; ++c) m = fmaxf(m, rp[r * 25 + c]);
        float sg = sigmoid_fast(m);
        v6 = sg;
        v5 = sg * ws[WS_TGTX + bf * 96 + r];
    }
    #pragma unroll
    for (int off = 32; off > 0; off >>= 1) {
        v0 += __shfl_down(v0, off, 64);
        v1 += __shfl_down(v1, off, 64);
        v2 += __shfl_down(v2, off, 64);
        v3 += __shfl_down(v3, off, 64);
        v4 += __shfl_down(v4, off, 64);
        v5 += __shfl_down(v5, off, 64);
        v6 += __shfl_down(v6, off, 64);
    }
    int wid = t >> 6, lane = t & 63;
    if (lane == 0) {
        red[wid][0] = v0; red[wid][1] = v1; red[wid][2] = v2; red[wid][3] = v3;
        red[wid][4] = v4; red[wid][5] = v5; red[wid][6] = v6;
    }
    __syncthreads();
    if (t == 0) {
        float* o = part + (size_t)((b * NQ + q) * NF + f) * 8;
        #pragma unroll
        for (int i = 0; i < 7; ++i)
            o[i] = red[0][i] + red[1][i] + red[2][i] + red[3][i] + red[4][i] + red[5][i];
    }
}

// ---------------------------------------------------------------------------
// combine: one thread per (b,q); part is contiguous 64 floats per thread
// ---------------------------------------------------------------------------
#define NTC 64
__global__ __launch_bounds__(NTC)
void combine_kernel(const float* __restrict__ logits, const float* __restrict__ boxes,
                    const float* __restrict__ tbox, const int* __restrict__ tvalid,
                    const float* __restrict__ ws, float* __restrict__ out) {
    int gid = blockIdx.x * NTC + threadIdx.x;
    if (gid >= 2 * NQ) return;
    int b = gid / NQ, q = gid - b * NQ;

    const float* pbase = ws + WS_PART + (size_t)gid * (NF * 8);
    float focal = 0.f, dnum = 0.f, dden = 0.f;
    float pYn = 0.f, pYd = 0.f, pXn = 0.f, pXd = 0.f;
    float tsum = 0.f, ysum = 0.f, xsum = 0.f;
    #pragma unroll
    for (int f = 0; f < NF; ++f) {
        int bf = b * NF + f;
        const float* p = pbase + f * 8;
        focal += p[0]; dnum += p[1]; dden += p[2];
        pYn += p[3]; pYd += p[4]; pXn += p[5]; pXd += p[6];
        tsum += ws[WS_TSUM + bf];
        ysum += ws[WS_YSUM + bf];
        xsum += ws[WS_XSUM + bf];
    }
    float cost_mask = focal / (float)DTOT;
    float cost_dice = -(2.f * dnum + 1.f) / (dden + tsum + 1.f);
    float coefY = (2.f * pYn + 1.f) / (pYd + ysum + 1.f);
    float coefX = (2.f * pXn + 1.f) / (pXd + xsum + 1.f);
    float cost_proj = -0.5f * (coefY + coefX);

    float wsum = 0.f, cls = 0.f, cb = 0.f, cg = 0.f;
    #pragma unroll
    for (int f = 0; f < NF; ++f) {
        float wv = (tvalid[b * NF + f] != 0) ? 1.f : 0.f;
        wsum += wv;
        float lg = logits[(b * NF + f) * NQ + q];
        float p = sigmoid_fast(lg);
        float negc = 0.75f * p * p * (-__logf(1.f - p + 1e-8f));
        float posc = 0.25f * (1.f - p) * (1.f - p) * (-__logf(p + 1e-8f));
        cls += (posc - negc) * wv;

        const float* bx = boxes + (size_t)((b * NF + f) * NQ + q) * 4;
        const float* tb = tbox + (b * NF + f) * 4;
        float cx = bx[0], cy = bx[1], bw = bx[2], bh = bx[3];
        float tcx = tb[0], tcy = tb[1], tbw = tb[2], tbh = tb[3];
        cb += fabsf(cx - tcx) + fabsf(cy - tcy) + fabsf(bw - tbw) + fabsf(bh - tbh);
        float sx1 = cx - 0.5f * bw, sy1 = cy - 0.5f * bh;
        float sx2 = cx + 0.5f * bw, sy2 = cy + 0.5f * bh;
        float tx1 = tcx - 0.5f * tbw, ty1 = tcy - 0.5f * tbh;
        float tx2 = tcx + 0.5f * tbw, ty2 = tcy + 0.5f * tbh;
        float a1 = (sx2 - sx1) * (sy2 - sy1), a2 = (tx2 - tx1) * (ty2 - ty1);
        float iw = fmaxf(fminf(sx2, tx2) - fmaxf(sx1, tx1), 0.f);
        float ih = fmaxf(fminf(sy2, ty2) - fmaxf(sy1, ty1), 0.f);
        float inter = iw * ih;
        float uni = a1 + a2 - inter;
        float iou = inter / uni;
        float cw = fmaxf(fmaxf(sx2, tx2) - fminf(sx1, tx1), 0.f);
        float chh = fmaxf(fmaxf(sy2, ty2) - fminf(sy1, ty1), 0.f);
        float areac = cw * chh;
        cg += -(iou - (areac - uni) / areac);
    }
    cls /= wsum;
    cb *= 0.125f;
    cg *= 0.125f;
    out[b * NQ + q] = cls + cb + cg + cost_mask + cost_dice + cost_proj;
}

#define NT 256
__global__ __launch_bounds__(NT)
void argmin_kernel(float* __restrict__ out, int write_idx) {
    int b = blockIdx.x, t = threadIdx.x;
    float best = INFINITY;
    int bi = 0x7fffffff;
    for (int q = t; q < NQ; q += NT) {
        float v = out[b * NQ + q];
        if (v < best) { best = v; bi = q; }
    }
    #pragma unroll
    for (int off = 32; off > 0; off >>= 1) {
        float ov = __shfl_down(best, off, 64);
        int oi = __shfl_down(bi, off, 64);
        if (ov < best || (ov == best && oi < bi)) { best = ov; bi = oi; }
    }
    __shared__ float rv[4];
    __shared__ int ri[4];
    int wid = t >> 6, lane = t & 63;
    if (lane == 0) { rv[wid] = best; ri[wid] = bi; }
    __syncthreads();
    if (t == 0 && write_idx) {
        #pragma unroll
        for (int w = 1; w < 4; ++w) {
            if (rv[w] < best || (rv[w] == best && ri[w] < bi)) { best = rv[w]; bi = ri[w]; }
        }
        out[2 * NQ + b] = (float)bi;       // src_ind
        out[2 * NQ + 2 + b] = 0.f;         // tgt_ind
    }
}

extern "C" void kernel_launch(void* const* d_in, const int* in_sizes, int n_in,
                              void* d_out, int out_size, void* d_ws, size_t ws_size,
                              hipStream_t stream) {
    const float* logits = (const float*)d_in[0];
    const float* boxes  = (const float*)d_in[1];
    const float* masks  = (const float*)d_in[2];
    const float* tmask  = (const float*)d_in[3];
    const float* tbox   = (const float*)d_in[4];
    const int*   tvalid = (const int*)d_in[5];
    const unsigned char* vpad = (const unsigned char*)d_in[6];
    float* out = (float*)d_out;
    float* ws  = (float*)d_ws;

    targets_kernel<<<NBF, NTT, 0, stream>>>(tmask, vpad, ws);
    partial_kernel<<<NBF * NQ, NTP, 0, stream>>>(masks, ws, ws + WS_PART);
    combine_kernel<<<(2 * NQ + NTC - 1) / NTC, NTC, 0, stream>>>(logits, boxes, tbox,
                                                                 tvalid, ws, out);
    int write_idx = (out_size >= 2 * NQ + 4) ? 1 : 0;
    argmin_kernel<<<2, NT, 0, stream>>>(out, write_idx);
}